// Round 1
// baseline (607.356 us; speedup 1.0000x reference)
//
#include <hip/hip_runtime.h>
#include <hip/hip_bf16.h>
#include <math.h>

// ---------------------------------------------------------------------------
// ImprovedDynamicCurvatureMLP on MI355X (gfx950)
// Pipeline:
//   x_bf  = bf16(x)
//   w_bf  = bf16(W1^T)         ; gemm_bt<tanh>    -> h_bf
//   w_bf  = bf16(W2^T)         ; gemm_bt<sigmoid> -> u_bf
//   v     = proj @ curv_feat   ; c[row] = sigmoid(x_row . v + cs)
//   z_bf  = a(row)*h + b(row)*u   (Poincare layer collapses to row scalars)
//   w_bf  = bf16(Wout^T)       ; gemm_bt<bias,f32> -> out
// ---------------------------------------------------------------------------

typedef __attribute__((ext_vector_type(8))) __bf16 bf16x8;
typedef __attribute__((ext_vector_type(4))) float  f32x4;

constexpr int BATCH = 4096;
constexpr int IND   = 4096;
constexpr int HIDD  = 4096;
constexpr int OUTD  = 1024;
constexpr float T_C  = 0.7f;
constexpr float MINC = 1e-5f;
constexpr float MAXC = 10.0f;
constexpr float EPSV = 1e-7f;

__device__ __forceinline__ float bf2f(unsigned int us) {
    return __uint_as_float(us << 16);
}
__device__ __forceinline__ unsigned short f2bf(float f) {
    unsigned int u = __float_as_uint(f);
    u = (u + 0x7FFFu + ((u >> 16) & 1u)) >> 16;   // round-to-nearest-even
    return (unsigned short)u;
}

// ---------------------------------------------------------------- cast f32->bf16
__global__ __launch_bounds__(256)
void cast_f32_bf16(const float* __restrict__ in, unsigned short* __restrict__ out, int n)
{
    const int n4 = n >> 2;
    for (int j = blockIdx.x * 256 + threadIdx.x; j < n4; j += gridDim.x * 256) {
        float4 v = ((const float4*)in)[j];
        ushort4 o;
        o.x = f2bf(v.x); o.y = f2bf(v.y); o.z = f2bf(v.z); o.w = f2bf(v.w);
        ((ushort4*)out)[j] = o;
    }
}

// ------------------------------------------------ transpose + cast: [K,N]f32 -> [N,K]bf16
__global__ __launch_bounds__(256)
void transpose_cast(const float* __restrict__ in, unsigned short* __restrict__ out,
                    int K, int N)
{
    __shared__ float tile[32][33];
    const int k0 = blockIdx.y * 32;
    const int n0 = blockIdx.x * 32;
    const int t = threadIdx.x;
    #pragma unroll
    for (int i = 0; i < 4; i++) {
        int idx = t + i * 256;
        int r = idx >> 5, c = idx & 31;
        tile[r][c] = in[(size_t)(k0 + r) * N + n0 + c];
    }
    __syncthreads();
    #pragma unroll
    for (int i = 0; i < 4; i++) {
        int idx = t + i * 256;
        int r = idx >> 5, c = idx & 31;    // r = n-offset, c = k-offset (coalesced in k)
        out[(size_t)(n0 + r) * K + k0 + c] = f2bf(tile[c][r]);
    }
}

// ---------------------------------------------------------------- GEMM (B^T input)
// A [M,K] bf16 row-major, Bt [N,K] bf16 row-major. 128x128 tile, BK=32, 4 waves.
// EPI: 0 = tanh(acc+bias)->bf16, 1 = sigmoid(acc+bias)->bf16, 2 = acc+bias->f32
template<int EPI>
__global__ __launch_bounds__(256)
void gemm_bt(const unsigned short* __restrict__ A,
             const unsigned short* __restrict__ Bt,
             const float* __restrict__ bias,
             void* __restrict__ outp,
             int N, int K)
{
    __shared__ unsigned short Asl[128 * 32];
    __shared__ unsigned short Bsl[128 * 32];

    const int t  = threadIdx.x;
    const int w  = t >> 6, l = t & 63;
    const int wr = w >> 1, wc = w & 1;
    const int row0 = blockIdx.y * 128;
    const int col0 = blockIdx.x * 128;

    const unsigned short* Ab = A  + (size_t)row0 * K;
    const unsigned short* Bb = Bt + (size_t)col0 * K;

    const int lr = l & 15;
    const int lk = (l >> 4) * 8;

    f32x4 acc[4][4] = {};

    for (int k0 = 0; k0 < K; k0 += 32) {
        __syncthreads();   // previous compute done before LDS overwrite
        #pragma unroll
        for (int q = 0; q < 2; q++) {
            int idx = q * 256 + t;          // chunk id in [0,512): 8 bf16 per chunk
            int r   = idx >> 2;             // row within tile (4 chunks/row of 32)
            int c8  = (idx & 3) * 8;
            __builtin_amdgcn_global_load_lds(
                (const __attribute__((address_space(1))) unsigned int*)(Ab + (size_t)r * K + k0 + c8),
                (__attribute__((address_space(3))) unsigned int*)(&Asl[idx * 8]),
                16, 0, 0);
            __builtin_amdgcn_global_load_lds(
                (const __attribute__((address_space(1))) unsigned int*)(Bb + (size_t)r * K + k0 + c8),
                (__attribute__((address_space(3))) unsigned int*)(&Bsl[idx * 8]),
                16, 0, 0);
        }
        __syncthreads();   // drains vmcnt+lgkmcnt

        bf16x8 af[4], bfr[4];
        #pragma unroll
        for (int mi = 0; mi < 4; mi++)
            af[mi] = *(const bf16x8*)(&Asl[(wr * 64 + mi * 16 + lr) * 32 + lk]);
        #pragma unroll
        for (int ni = 0; ni < 4; ni++)
            bfr[ni] = *(const bf16x8*)(&Bsl[(wc * 64 + ni * 16 + lr) * 32 + lk]);

        #pragma unroll
        for (int mi = 0; mi < 4; mi++)
            #pragma unroll
            for (int ni = 0; ni < 4; ni++)
                acc[mi][ni] = __builtin_amdgcn_mfma_f32_16x16x32_bf16(
                    af[mi], bfr[ni], acc[mi][ni], 0, 0, 0);
    }

    // epilogue: D row=(l>>4)*4+r, col=l&15 within each 16x16 tile
    const int colb = col0 + wc * 64;
    const int rowb = row0 + wr * 64 + (l >> 4) * 4;
    #pragma unroll
    for (int ni = 0; ni < 4; ni++) {
        const int cg = colb + ni * 16 + lr;
        const float bv = bias[cg];
        #pragma unroll
        for (int mi = 0; mi < 4; mi++) {
            #pragma unroll
            for (int r = 0; r < 4; r++) {
                const int rg = rowb + mi * 16 + r;
                float v = acc[mi][ni][r] + bv;
                if constexpr (EPI == 0) {
                    v = tanhf(v);
                    ((unsigned short*)outp)[(size_t)rg * N + cg] = f2bf(v);
                } else if constexpr (EPI == 1) {
                    v = 1.0f / (1.0f + expf(-v));
                    ((unsigned short*)outp)[(size_t)rg * N + cg] = f2bf(v);
                } else {
                    ((float*)outp)[(size_t)rg * N + cg] = v;
                }
            }
        }
    }
}

// ---------------------------------------------------------------- v = proj @ curv_feat
__global__ __launch_bounds__(256)
void proj_cf(const float* __restrict__ proj, const float* __restrict__ cf,
             float* __restrict__ v)
{
    int i = blockIdx.x * 256 + threadIdx.x;
    if (i < IND) {
        float s = 0.f;
        #pragma unroll
        for (int j = 0; j < 16; j++) s += proj[i * 16 + j] * cf[j];
        v[i] = s;
    }
}

// ---------------------------------------------------------------- per-row curvature
__global__ __launch_bounds__(256)
void curv_kernel(const float* __restrict__ x, const float* __restrict__ v,
                 const float* __restrict__ cs, float* __restrict__ c)
{
    const int row = blockIdx.x;
    const float* xr = x + (size_t)row * IND;
    float s = 0.f;
    for (int j = threadIdx.x; j < IND; j += 256) s += xr[j] * v[j];
    #pragma unroll
    for (int o = 32; o > 0; o >>= 1) s += __shfl_down(s, o, 64);
    __shared__ float red[4];
    if ((threadIdx.x & 63) == 0) red[threadIdx.x >> 6] = s;
    __syncthreads();
    if (threadIdx.x == 0) {
        float tot = red[0] + red[1] + red[2] + red[3];
        float adj = 1.0f / (1.0f + expf(-(tot + cs[0])));
        float cc  = MINC + (MAXC - MINC) * adj;
        c[row] = fminf(fmaxf(cc, MINC), MAXC);
    }
}

// ---------------------------------------------------------------- Poincare layer
// z = a(row)*h + b(row)*u  where a,b come from ||h||^2, ||u||^2, <h,u>, c(row).
__global__ __launch_bounds__(256)
void poincare_kernel(const unsigned short* __restrict__ hb,
                     const unsigned short* __restrict__ ub,
                     const float* __restrict__ c,
                     unsigned short* __restrict__ zb)
{
    const int row = blockIdx.x;
    const int t = threadIdx.x;
    const size_t base = (size_t)row * HIDD;

    float hv[16], uv[16];
    float h2 = 0.f, u2 = 0.f, hu = 0.f;
    #pragma unroll
    for (int q = 0; q < 2; q++) {
        const int e0 = (q * 256 + t) * 8;
        uint4 hc = *(const uint4*)(hb + base + e0);
        uint4 uc = *(const uint4*)(ub + base + e0);
        const unsigned int hw[4] = {hc.x, hc.y, hc.z, hc.w};
        const unsigned int uw[4] = {uc.x, uc.y, uc.z, uc.w};
        #pragma unroll
        for (int i = 0; i < 4; i++) {
            float h0 = bf2f(hw[i] & 0xFFFFu), h1 = bf2f(hw[i] >> 16);
            float u0 = bf2f(uw[i] & 0xFFFFu), u1 = bf2f(uw[i] >> 16);
            hv[q * 8 + 2 * i]     = h0; hv[q * 8 + 2 * i + 1] = h1;
            uv[q * 8 + 2 * i]     = u0; uv[q * 8 + 2 * i + 1] = u1;
            h2 += h0 * h0 + h1 * h1;
            u2 += u0 * u0 + u1 * u1;
            hu += h0 * u0 + h1 * u1;
        }
    }
    #pragma unroll
    for (int o = 32; o > 0; o >>= 1) {
        h2 += __shfl_down(h2, o, 64);
        u2 += __shfl_down(u2, o, 64);
        hu += __shfl_down(hu, o, 64);
    }
    __shared__ float red[3][4];
    const int w = t >> 6;
    if ((t & 63) == 0) { red[0][w] = h2; red[1][w] = u2; red[2][w] = hu; }
    __syncthreads();
    h2 = red[0][0] + red[0][1] + red[0][2] + red[0][3];
    u2 = red[1][0] + red[1][1] + red[1][2] + red[1][3];
    hu = red[2][0] + red[2][1] + red[2][2] + red[2][3];

    const float cc = c[row];
    const float sc = sqrtf(cc);
    float nh = fmaxf(sqrtf(h2), EPSV);
    float nu = fmaxf(sqrtf(u2), EPSV);
    float ah = fminf(fmaxf(sc * nh, EPSV), 1.0f - 1e-5f);
    float au = fminf(fmaxf(sc * nu, EPSV), 1.0f - 1e-5f);
    float ath = 0.5f * log1pf(2.0f * ah / (1.0f - ah));   // artanh
    float atu = 0.5f * log1pf(2.0f * au / (1.0f - au));
    float alpha = tanhf((1.0f - T_C) * ath) / (sc * nh);
    float beta  = tanhf(T_C * atu) / (sc * nu);
    float x2 = alpha * alpha * h2;
    float y2 = beta * beta * u2;
    float xy = alpha * beta * hu;
    float den = 1.0f + 2.0f * cc * xy + cc * cc * x2 * y2;
    den = fmaxf(den, EPSV);
    float ca = (1.0f + 2.0f * cc * xy + cc * y2) * alpha / den;
    float cb = (1.0f - cc * x2) * beta / den;
    if (isnan(ca) || isnan(cb)) { ca = 1.0f; cb = 0.0f; }   // NaN row -> fallback to h

    #pragma unroll
    for (int q = 0; q < 2; q++) {
        const int e0 = (q * 256 + t) * 8;
        unsigned int ow[4];
        #pragma unroll
        for (int i = 0; i < 4; i++) {
            float z0 = ca * hv[q * 8 + 2 * i]     + cb * uv[q * 8 + 2 * i];
            float z1 = ca * hv[q * 8 + 2 * i + 1] + cb * uv[q * 8 + 2 * i + 1];
            ow[i] = (unsigned int)f2bf(z0) | ((unsigned int)f2bf(z1) << 16);
        }
        *(uint4*)(zb + base + e0) = make_uint4(ow[0], ow[1], ow[2], ow[3]);
    }
}

// ---------------------------------------------------------------------------
extern "C" void kernel_launch(void* const* d_in, const int* in_sizes, int n_in,
                              void* d_out, int out_size, void* d_ws, size_t ws_size,
                              hipStream_t stream)
{
    const float* x    = (const float*)d_in[0];
    const float* W1   = (const float*)d_in[1];
    const float* b1   = (const float*)d_in[2];
    const float* W2   = (const float*)d_in[3];
    const float* b2   = (const float*)d_in[4];
    const float* Wout = (const float*)d_in[5];
    const float* bout = (const float*)d_in[6];
    const float* cf   = (const float*)d_in[7];
    const float* cs   = (const float*)d_in[8];
    const float* proj = (const float*)d_in[9];
    float* out = (float*)d_out;

    char* ws = (char*)d_ws;
    unsigned short* x_bf = (unsigned short*)(ws);               // 32 MiB (reused as z_bf)
    unsigned short* w_bf = (unsigned short*)(ws + (33554432));  // 32 MiB (W1T/W2T/WoutT)
    unsigned short* h_bf = (unsigned short*)(ws + (67108864));  // 32 MiB
    unsigned short* u_bf = (unsigned short*)(ws + (100663296)); // 32 MiB
    float* vvec = (float*)(ws + 134217728);                     // 16 KiB
    float* cvec = (float*)(ws + 134217728 + 16384);             // 16 KiB

    // 1. casts / curvature prep
    cast_f32_bf16<<<2048, 256, 0, stream>>>(x, x_bf, BATCH * IND);
    proj_cf<<<IND / 256, 256, 0, stream>>>(proj, cf, vvec);
    curv_kernel<<<BATCH, 256, 0, stream>>>(x, vvec, cs, cvec);

    // 2. h = tanh(x @ W1 + b1)
    transpose_cast<<<dim3(HIDD / 32, IND / 32), 256, 0, stream>>>(W1, w_bf, IND, HIDD);
    gemm_bt<0><<<dim3(HIDD / 128, BATCH / 128), 256, 0, stream>>>(x_bf, w_bf, b1, h_bf, HIDD, IND);

    // 3. u = sigmoid(h @ W2 + b2)
    transpose_cast<<<dim3(HIDD / 32, HIDD / 32), 256, 0, stream>>>(W2, w_bf, HIDD, HIDD);
    gemm_bt<1><<<dim3(HIDD / 128, BATCH / 128), 256, 0, stream>>>(h_bf, w_bf, b2, u_bf, HIDD, HIDD);

    // 4. z = poincare(h, u, c)   (z overwrites x_bf)
    poincare_kernel<<<BATCH, 256, 0, stream>>>(h_bf, u_bf, cvec, x_bf);

    // 5. out = z @ Wout + bout
    transpose_cast<<<dim3(OUTD / 32, HIDD / 32), 256, 0, stream>>>(Wout, w_bf, HIDD, OUTD);
    gemm_bt<2><<<dim3(OUTD / 128, BATCH / 128), 256, 0, stream>>>(x_bf, w_bf, bout, out, OUTD, HIDD);
}

// Round 2
// 453.206 us; speedup vs baseline: 1.3401x; 1.3401x over previous
//
#include <hip/hip_runtime.h>
#include <hip/hip_bf16.h>
#include <math.h>

// ---------------------------------------------------------------------------
// ImprovedDynamicCurvatureMLP on MI355X (gfx950)
//   x_bf  = bf16(x)
//   h_bf  = gemm256<tanh>(x_bf, W1^T)        [256^2 8-wave deep-pipelined]
//   u_bf  = gemm256<sigmoid>(h_bf, W2^T)
//   c     = sigmoid(x @ (proj@curv_feat) + cs)  -> per-row curvature
//   z_bf  = a(row)*h + b(row)*u               (Poincare layer = row scalars)
//   out   = gemm_bt<f32>(z_bf, Wout^T)        [128^2, N=1024 -> 256 blocks]
// ---------------------------------------------------------------------------

typedef __attribute__((ext_vector_type(8))) __bf16 bf16x8;
typedef __attribute__((ext_vector_type(4))) float  f32x4;

constexpr int BATCH = 4096;
constexpr int IND   = 4096;
constexpr int HIDD  = 4096;
constexpr int OUTD  = 1024;
constexpr float T_C  = 0.7f;
constexpr float MINC = 1e-5f;
constexpr float MAXC = 10.0f;
constexpr float EPSV = 1e-7f;

__device__ __forceinline__ float bf2f(unsigned int us) {
    return __uint_as_float(us << 16);
}
__device__ __forceinline__ unsigned short f2bf(float f) {
    unsigned int u = __float_as_uint(f);
    u = (u + 0x7FFFu + ((u >> 16) & 1u)) >> 16;   // round-to-nearest-even
    return (unsigned short)u;
}

// ---------------------------------------------------------------- cast f32->bf16
__global__ __launch_bounds__(256)
void cast_f32_bf16(const float* __restrict__ in, unsigned short* __restrict__ out, int n)
{
    const int n4 = n >> 2;
    for (int j = blockIdx.x * 256 + threadIdx.x; j < n4; j += gridDim.x * 256) {
        float4 v = ((const float4*)in)[j];
        ushort4 o;
        o.x = f2bf(v.x); o.y = f2bf(v.y); o.z = f2bf(v.z); o.w = f2bf(v.w);
        ((ushort4*)out)[j] = o;
    }
}

// ------------------------------------------------ transpose + cast: [K,N]f32 -> [N,K]bf16
__global__ __launch_bounds__(256)
void transpose_cast(const float* __restrict__ in, unsigned short* __restrict__ out,
                    int K, int N)
{
    __shared__ float tile[32][33];
    const int k0 = blockIdx.y * 32;
    const int n0 = blockIdx.x * 32;
    const int t = threadIdx.x;
    #pragma unroll
    for (int i = 0; i < 4; i++) {
        int idx = t + i * 256;
        int r = idx >> 5, c = idx & 31;
        tile[r][c] = in[(size_t)(k0 + r) * N + n0 + c];
    }
    __syncthreads();
    #pragma unroll
    for (int i = 0; i < 4; i++) {
        int idx = t + i * 256;
        int r = idx >> 5, c = idx & 31;
        out[(size_t)(n0 + r) * K + k0 + c] = f2bf(tile[c][r]);
    }
}

// ---------------------------------------------------------------- 256^2 GEMM (B^T)
// A [M,K] bf16 rm, Bt [N,K] bf16 rm. BM=BN=256, BK=64, 512 thr = 8 waves (2Mx4N).
// Deep pipeline: dbuf LDS, tile t+1 staged (global_load_lds, pre-swizzled src)
// at tile-t start; 4 phases of {ds_read ; setprio(1); 16 MFMA; setprio(0); bar};
// one vmcnt(0)+barrier per tile boundary. LDS XOR swizzle: colbyte ^= (row&7)<<4.
// EPI: 0 = tanh->bf16, 1 = sigmoid->bf16
template<int EPI>
__global__ __launch_bounds__(512)
void gemm256(const unsigned short* __restrict__ A,
             const unsigned short* __restrict__ Bt,
             const float* __restrict__ bias,
             unsigned short* __restrict__ outp,
             int N, int K)
{
    __shared__ unsigned short lds[4 * 256 * 64];    // A[2][256][64] | B[2][256][64], 128 KiB
    unsigned short* Al = lds;
    unsigned short* Bl = lds + 2 * 256 * 64;

    const int t = threadIdx.x;
    const int w = t >> 6, l = t & 63;
    const int wr = w >> 2, wc = w & 3;      // wave grid 2 x 4
    const int lr = l & 15, lg = l >> 4;     // frag row lane, k-group

    // bijective XCD swizzle (nwg = 256, divisible by 8)
    const int nwg = gridDim.x * gridDim.y;
    const int bid = blockIdx.y * gridDim.x + blockIdx.x;
    const int q8 = nwg >> 3, r8 = nwg & 7;
    const int xcd = bid & 7, off = bid >> 3;
    const int wgid = (xcd < r8 ? xcd * (q8 + 1) : r8 * (q8 + 1) + (xcd - r8) * q8) + off;
    const int by = wgid / gridDim.x;
    const int bx = wgid % gridDim.x;

    const int row0 = by * 256, col0 = bx * 256;
    const unsigned short* Ab = A  + (size_t)row0 * K;
    const unsigned short* Bb = Bt + (size_t)col0 * K;
    const int NT = K >> 6;

    f32x4 acc[8][4] = {};

    // ---- staging: 8 global_load_lds (2 per half-tile), source pre-swizzled ----
    auto stage = [&](int kt, int buf) {
        const int kb = kt * 128;            // byte offset of K-tile within a row
        #pragma unroll
        for (int s = 0; s < 8; s++) {
            const int mat = s >> 2;         // 0 = A, 1 = B
            const int h   = (s >> 1) & 1;   // half (rows 0-127 / 128-255)
            const int qq  = s & 1;
            const int id  = qq * 512 + t;   // chunk within half
            const int row = h * 128 + (id >> 3);
            const int cb  = (id & 7) * 16;
            const int scb = cb ^ ((row & 7) << 4);
            const char* src = (const char*)(mat ? Bb : Ab)
                            + (size_t)row * ((size_t)K * 2) + kb + scb;
            unsigned short* dst = (mat ? Bl : Al) + buf * 16384 + h * 8192 + id * 8;
            __builtin_amdgcn_global_load_lds(
                (const __attribute__((address_space(1))) unsigned int*)src,
                (__attribute__((address_space(3))) unsigned int*)dst, 16, 0, 0);
        }
    };

    stage(0, 0);
    asm volatile("s_waitcnt vmcnt(0)" ::: "memory");
    __builtin_amdgcn_s_barrier();

    const int sw = (lr & 7) << 4;
    for (int kt = 0; kt < NT; ++kt) {
        const int buf = kt & 1;
        if (kt + 1 < NT) stage(kt + 1, buf ^ 1);

        const char* AlB = (const char*)Al + buf * 32768 + (wr * 128 + lr) * 128;
        const char* BlB = (const char*)Bl + buf * 32768 + (wc * 64 + lr) * 128;
        const int c0 = (lg * 16) ^ sw;          // kk = 0 swizzled col byte
        const int c1 = (64 + lg * 16) ^ sw;     // kk = 1

        bf16x8 bf[4][2];
        #pragma unroll
        for (int ni = 0; ni < 4; ni++) {
            bf[ni][0] = *(const bf16x8*)(BlB + ni * 2048 + c0);
            bf[ni][1] = *(const bf16x8*)(BlB + ni * 2048 + c1);
        }

        #pragma unroll
        for (int p = 0; p < 4; p++) {
            bf16x8 af[2][2];
            #pragma unroll
            for (int ms = 0; ms < 2; ms++) {
                af[ms][0] = *(const bf16x8*)(AlB + (2 * p + ms) * 2048 + c0);
                af[ms][1] = *(const bf16x8*)(AlB + (2 * p + ms) * 2048 + c1);
            }
            __builtin_amdgcn_s_setprio(1);
            #pragma unroll
            for (int ms = 0; ms < 2; ms++)
                #pragma unroll
                for (int ni = 0; ni < 4; ni++) {
                    acc[2 * p + ms][ni] = __builtin_amdgcn_mfma_f32_16x16x32_bf16(
                        af[ms][0], bf[ni][0], acc[2 * p + ms][ni], 0, 0, 0);
                    acc[2 * p + ms][ni] = __builtin_amdgcn_mfma_f32_16x16x32_bf16(
                        af[ms][1], bf[ni][1], acc[2 * p + ms][ni], 0, 0, 0);
                }
            __builtin_amdgcn_s_setprio(0);
            if (p < 3) __builtin_amdgcn_s_barrier();   // pacing only (no drain)
        }
        asm volatile("s_waitcnt vmcnt(0)" ::: "memory");   // tile t+1 fully staged
        __builtin_amdgcn_s_barrier();
    }

    // epilogue: D row = (l>>4)*4 + r, col = lr within each 16x16 frag
    const int colb = col0 + wc * 64;
    const int rowb = row0 + wr * 128 + lg * 4;
    #pragma unroll
    for (int ni = 0; ni < 4; ni++) {
        const int cg = colb + ni * 16 + lr;
        const float bv = bias[cg];
        #pragma unroll
        for (int mi = 0; mi < 8; mi++) {
            #pragma unroll
            for (int r = 0; r < 4; r++) {
                const int rg = rowb + mi * 16 + r;
                float v = acc[mi][ni][r] + bv;
                if constexpr (EPI == 0) v = tanhf(v);
                else                    v = 1.0f / (1.0f + expf(-v));
                outp[(size_t)rg * N + cg] = f2bf(v);
            }
        }
    }
}

// ---------------------------------------------------------------- 128^2 GEMM (B^T), f32 out
__global__ __launch_bounds__(256)
void gemm_bt_f32(const unsigned short* __restrict__ A,
                 const unsigned short* __restrict__ Bt,
                 const float* __restrict__ bias,
                 float* __restrict__ outp,
                 int N, int K)
{
    __shared__ unsigned short Asl[128 * 32];
    __shared__ unsigned short Bsl[128 * 32];

    const int t  = threadIdx.x;
    const int w  = t >> 6, l = t & 63;
    const int wr = w >> 1, wc = w & 1;
    const int row0 = blockIdx.y * 128;
    const int col0 = blockIdx.x * 128;

    const unsigned short* Ab = A  + (size_t)row0 * K;
    const unsigned short* Bb = Bt + (size_t)col0 * K;

    const int lr = l & 15;
    const int lk = (l >> 4) * 8;

    f32x4 acc[4][4] = {};

    for (int k0 = 0; k0 < K; k0 += 32) {
        __syncthreads();
        #pragma unroll
        for (int q = 0; q < 2; q++) {
            int idx = q * 256 + t;
            int r   = idx >> 2;
            int c8  = (idx & 3) * 8;
            __builtin_amdgcn_global_load_lds(
                (const __attribute__((address_space(1))) unsigned int*)(Ab + (size_t)r * K + k0 + c8),
                (__attribute__((address_space(3))) unsigned int*)(&Asl[idx * 8]), 16, 0, 0);
            __builtin_amdgcn_global_load_lds(
                (const __attribute__((address_space(1))) unsigned int*)(Bb + (size_t)r * K + k0 + c8),
                (__attribute__((address_space(3))) unsigned int*)(&Bsl[idx * 8]), 16, 0, 0);
        }
        __syncthreads();

        bf16x8 af[4], bfr[4];
        #pragma unroll
        for (int mi = 0; mi < 4; mi++)
            af[mi] = *(const bf16x8*)(&Asl[(wr * 64 + mi * 16 + lr) * 32 + lk]);
        #pragma unroll
        for (int ni = 0; ni < 4; ni++)
            bfr[ni] = *(const bf16x8*)(&Bsl[(wc * 64 + ni * 16 + lr) * 32 + lk]);

        #pragma unroll
        for (int mi = 0; mi < 4; mi++)
            #pragma unroll
            for (int ni = 0; ni < 4; ni++)
                acc[mi][ni] = __builtin_amdgcn_mfma_f32_16x16x32_bf16(
                    af[mi], bfr[ni], acc[mi][ni], 0, 0, 0);
    }

    const int colb = col0 + wc * 64;
    const int rowb = row0 + wr * 64 + (l >> 4) * 4;
    #pragma unroll
    for (int ni = 0; ni < 4; ni++) {
        const int cg = colb + ni * 16 + lr;
        const float bv = bias[cg];
        #pragma unroll
        for (int mi = 0; mi < 4; mi++)
            #pragma unroll
            for (int r = 0; r < 4; r++)
                outp[(size_t)(rowb + mi * 16 + r) * N + cg] = acc[mi][ni][r] + bv;
    }
}

// ---------------------------------------------------------------- v = proj @ curv_feat
__global__ __launch_bounds__(256)
void proj_cf(const float* __restrict__ proj, const float* __restrict__ cf,
             float* __restrict__ v)
{
    int i = blockIdx.x * 256 + threadIdx.x;
    if (i < IND) {
        float s = 0.f;
        #pragma unroll
        for (int j = 0; j < 16; j++) s += proj[i * 16 + j] * cf[j];
        v[i] = s;
    }
}

// ---------------------------------------------------------------- per-row curvature
__global__ __launch_bounds__(256)
void curv_kernel(const float* __restrict__ x, const float* __restrict__ v,
                 const float* __restrict__ cs, float* __restrict__ c)
{
    const int row = blockIdx.x;
    const float* xr = x + (size_t)row * IND;
    float s = 0.f;
    for (int j = threadIdx.x; j < IND; j += 256) s += xr[j] * v[j];
    #pragma unroll
    for (int o = 32; o > 0; o >>= 1) s += __shfl_down(s, o, 64);
    __shared__ float red[4];
    if ((threadIdx.x & 63) == 0) red[threadIdx.x >> 6] = s;
    __syncthreads();
    if (threadIdx.x == 0) {
        float tot = red[0] + red[1] + red[2] + red[3];
        float adj = 1.0f / (1.0f + expf(-(tot + cs[0])));
        float cc  = MINC + (MAXC - MINC) * adj;
        c[row] = fminf(fmaxf(cc, MINC), MAXC);
    }
}

// ---------------------------------------------------------------- Poincare layer
__global__ __launch_bounds__(256)
void poincare_kernel(const unsigned short* __restrict__ hb,
                     const unsigned short* __restrict__ ub,
                     const float* __restrict__ c,
                     unsigned short* __restrict__ zb)
{
    const int row = blockIdx.x;
    const int t = threadIdx.x;
    const size_t base = (size_t)row * HIDD;

    float hv[16], uv[16];
    float h2 = 0.f, u2 = 0.f, hu = 0.f;
    #pragma unroll
    for (int q = 0; q < 2; q++) {
        const int e0 = (q * 256 + t) * 8;
        uint4 hc = *(const uint4*)(hb + base + e0);
        uint4 uc = *(const uint4*)(ub + base + e0);
        const unsigned int hw[4] = {hc.x, hc.y, hc.z, hc.w};
        const unsigned int uw[4] = {uc.x, uc.y, uc.z, uc.w};
        #pragma unroll
        for (int i = 0; i < 4; i++) {
            float h0 = bf2f(hw[i] & 0xFFFFu), h1 = bf2f(hw[i] >> 16);
            float u0 = bf2f(uw[i] & 0xFFFFu), u1 = bf2f(uw[i] >> 16);
            hv[q * 8 + 2 * i]     = h0; hv[q * 8 + 2 * i + 1] = h1;
            uv[q * 8 + 2 * i]     = u0; uv[q * 8 + 2 * i + 1] = u1;
            h2 += h0 * h0 + h1 * h1;
            u2 += u0 * u0 + u1 * u1;
            hu += h0 * u0 + h1 * u1;
        }
    }
    #pragma unroll
    for (int o = 32; o > 0; o >>= 1) {
        h2 += __shfl_down(h2, o, 64);
        u2 += __shfl_down(u2, o, 64);
        hu += __shfl_down(hu, o, 64);
    }
    __shared__ float red[3][4];
    const int w = t >> 6;
    if ((t & 63) == 0) { red[0][w] = h2; red[1][w] = u2; red[2][w] = hu; }
    __syncthreads();
    h2 = red[0][0] + red[0][1] + red[0][2] + red[0][3];
    u2 = red[1][0] + red[1][1] + red[1][2] + red[1][3];
    hu = red[2][0] + red[2][1] + red[2][2] + red[2][3];

    const float cc = c[row];
    const float sc = sqrtf(cc);
    float nh = fmaxf(sqrtf(h2), EPSV);
    float nu = fmaxf(sqrtf(u2), EPSV);
    float ah = fminf(fmaxf(sc * nh, EPSV), 1.0f - 1e-5f);
    float au = fminf(fmaxf(sc * nu, EPSV), 1.0f - 1e-5f);
    float ath = 0.5f * log1pf(2.0f * ah / (1.0f - ah));
    float atu = 0.5f * log1pf(2.0f * au / (1.0f - au));
    float alpha = tanhf((1.0f - T_C) * ath) / (sc * nh);
    float beta  = tanhf(T_C * atu) / (sc * nu);
    float x2 = alpha * alpha * h2;
    float y2 = beta * beta * u2;
    float xy = alpha * beta * hu;
    float den = 1.0f + 2.0f * cc * xy + cc * cc * x2 * y2;
    den = fmaxf(den, EPSV);
    float ca = (1.0f + 2.0f * cc * xy + cc * y2) * alpha / den;
    float cb = (1.0f - cc * x2) * beta / den;
    if (isnan(ca) || isnan(cb)) { ca = 1.0f; cb = 0.0f; }

    #pragma unroll
    for (int q = 0; q < 2; q++) {
        const int e0 = (q * 256 + t) * 8;
        unsigned int ow[4];
        #pragma unroll
        for (int i = 0; i < 4; i++) {
            float z0 = ca * hv[q * 8 + 2 * i]     + cb * uv[q * 8 + 2 * i];
            float z1 = ca * hv[q * 8 + 2 * i + 1] + cb * uv[q * 8 + 2 * i + 1];
            ow[i] = (unsigned int)f2bf(z0) | ((unsigned int)f2bf(z1) << 16);
        }
        *(uint4*)(zb + base + e0) = make_uint4(ow[0], ow[1], ow[2], ow[3]);
    }
}

// ---------------------------------------------------------------------------
extern "C" void kernel_launch(void* const* d_in, const int* in_sizes, int n_in,
                              void* d_out, int out_size, void* d_ws, size_t ws_size,
                              hipStream_t stream)
{
    const float* x    = (const float*)d_in[0];
    const float* W1   = (const float*)d_in[1];
    const float* b1   = (const float*)d_in[2];
    const float* W2   = (const float*)d_in[3];
    const float* b2   = (const float*)d_in[4];
    const float* Wout = (const float*)d_in[5];
    const float* bout = (const float*)d_in[6];
    const float* cf   = (const float*)d_in[7];
    const float* cs   = (const float*)d_in[8];
    const float* proj = (const float*)d_in[9];
    float* out = (float*)d_out;

    char* ws = (char*)d_ws;
    unsigned short* x_bf = (unsigned short*)(ws);               // 32 MiB (reused as z_bf)
    unsigned short* w_bf = (unsigned short*)(ws + (33554432));  // 32 MiB (W1T/W2T/WoutT)
    unsigned short* h_bf = (unsigned short*)(ws + (67108864));  // 32 MiB
    unsigned short* u_bf = (unsigned short*)(ws + (100663296)); // 32 MiB
    float* vvec = (float*)(ws + 134217728);                     // 16 KiB
    float* cvec = (float*)(ws + 134217728 + 16384);             // 16 KiB

    // 1. casts / curvature prep
    cast_f32_bf16<<<2048, 256, 0, stream>>>(x, x_bf, BATCH * IND);
    proj_cf<<<IND / 256, 256, 0, stream>>>(proj, cf, vvec);
    curv_kernel<<<BATCH, 256, 0, stream>>>(x, vvec, cs, cvec);

    // 2. h = tanh(x @ W1 + b1)
    transpose_cast<<<dim3(HIDD / 32, IND / 32), 256, 0, stream>>>(W1, w_bf, IND, HIDD);
    gemm256<0><<<dim3(HIDD / 256, BATCH / 256), 512, 0, stream>>>(x_bf, w_bf, b1, h_bf, HIDD, IND);

    // 3. u = sigmoid(h @ W2 + b2)
    transpose_cast<<<dim3(HIDD / 32, HIDD / 32), 256, 0, stream>>>(W2, w_bf, HIDD, HIDD);
    gemm256<1><<<dim3(HIDD / 256, BATCH / 256), 512, 0, stream>>>(h_bf, w_bf, b2, u_bf, HIDD, HIDD);

    // 4. z = poincare(h, u, c)   (z overwrites x_bf)
    poincare_kernel<<<BATCH, 256, 0, stream>>>(h_bf, u_bf, cvec, x_bf);

    // 5. out = z @ Wout + bout
    transpose_cast<<<dim3(OUTD / 32, HIDD / 32), 256, 0, stream>>>(Wout, w_bf, HIDD, OUTD);
    gemm_bt_f32<<<dim3(OUTD / 128, BATCH / 128), 256, 0, stream>>>(x_bf, w_bf, bout, out, OUTD, HIDD);
}

// Round 3
// 433.140 us; speedup vs baseline: 1.4022x; 1.0463x over previous
//
#include <hip/hip_runtime.h>
#include <hip/hip_bf16.h>
#include <math.h>

// ---------------------------------------------------------------------------
// ImprovedDynamicCurvatureMLP on MI355X (gfx950)
//   x_bf,c = fused cast + per-row curvature
//   h_bf  = gemm256<tanh>(x_bf, W1^T)     [256^2, 8-wave, counted-vmcnt pipeline]
//   u_bf  = gemm256<sigmoid>(h_bf, W2^T)
//   z_bf  = a(row)*h + b(row)*u          (Poincare layer = row scalars)
//   out   = gemm_bt_f32(z_bf, Wout^T)    [128^2, N=1024 -> 256 blocks]
// ---------------------------------------------------------------------------

typedef __attribute__((ext_vector_type(8))) __bf16 bf16x8;
typedef __attribute__((ext_vector_type(4))) float  f32x4;

constexpr int BATCH = 4096;
constexpr int IND   = 4096;
constexpr int HIDD  = 4096;
constexpr int OUTD  = 1024;
constexpr float T_C  = 0.7f;
constexpr float MINC = 1e-5f;
constexpr float MAXC = 10.0f;
constexpr float EPSV = 1e-7f;

__device__ __forceinline__ float bf2f(unsigned int us) {
    return __uint_as_float(us << 16);
}
__device__ __forceinline__ unsigned short f2bf(float f) {
    unsigned int u = __float_as_uint(f);
    u = (u + 0x7FFFu + ((u >> 16) & 1u)) >> 16;   // round-to-nearest-even
    return (unsigned short)u;
}

// ------------------------------------------ fused cast f32->bf16 + row dot(x,v)
__global__ __launch_bounds__(256)
void cast_curv(const float* __restrict__ x, const float* __restrict__ v,
               const float* __restrict__ cs,
               unsigned short* __restrict__ xb, float* __restrict__ c)
{
    const int row = blockIdx.x;
    const float* xr = x + (size_t)row * IND;
    unsigned short* ob = xb + (size_t)row * IND;
    float s = 0.f;
    for (int i = threadIdx.x; i < IND / 4; i += 256) {
        float4 w  = ((const float4*)xr)[i];
        float4 vv = ((const float4*)v)[i];
        s += w.x * vv.x + w.y * vv.y + w.z * vv.z + w.w * vv.w;
        ushort4 o;
        o.x = f2bf(w.x); o.y = f2bf(w.y); o.z = f2bf(w.z); o.w = f2bf(w.w);
        ((ushort4*)ob)[i] = o;
    }
    #pragma unroll
    for (int o = 32; o > 0; o >>= 1) s += __shfl_down(s, o, 64);
    __shared__ float red[4];
    if ((threadIdx.x & 63) == 0) red[threadIdx.x >> 6] = s;
    __syncthreads();
    if (threadIdx.x == 0) {
        float tot = red[0] + red[1] + red[2] + red[3];
        float adj = 1.0f / (1.0f + expf(-(tot + cs[0])));
        float cc  = MINC + (MAXC - MINC) * adj;
        c[row] = fminf(fmaxf(cc, MINC), MAXC);
    }
}

// ------------------------------------------------ transpose + cast: [K,N]f32 -> [N,K]bf16
__global__ __launch_bounds__(256)
void transpose_cast(const float* __restrict__ in, unsigned short* __restrict__ out,
                    int K, int N)
{
    __shared__ float tile[32][33];
    const int k0 = blockIdx.y * 32;
    const int n0 = blockIdx.x * 32;
    const int t = threadIdx.x;
    #pragma unroll
    for (int i = 0; i < 4; i++) {
        int idx = t + i * 256;
        int r = idx >> 5, c = idx & 31;
        tile[r][c] = in[(size_t)(k0 + r) * N + n0 + c];
    }
    __syncthreads();
    #pragma unroll
    for (int i = 0; i < 4; i++) {
        int idx = t + i * 256;
        int r = idx >> 5, c = idx & 31;
        out[(size_t)(n0 + r) * K + k0 + c] = f2bf(tile[c][r]);
    }
}

// ---------------------------------------------------------------- 256^2 GEMM (B^T)
// A [M,K] bf16 rm, Bt [N,K] bf16 rm. BM=BN=256, BK=64, 512 thr = 8 waves (2Mx4N).
// Counted-vmcnt pipeline (T3+T4): per-phase half-tile staging into buf^1;
// wave m-frags strided 32 rows so phases 0-1 read A-half0 only, 2-3 A-half1.
// Issue during tile t: p0->A-h0(t+1), p1->B-h0(t+1), p2->B-h1(t+1), p3->A-h1(t+1).
// Waits: end p1 vmcnt(4)  [A-h1(t) landed; outst = Ah1(t)+Ah0(t+1)+Bh0(t+1)=6]
//        end p3 vmcnt(2)  [Ah0/Bh0/Bh1(t+1) landed; Ah1(t+1) stays in flight]
// Each wait precedes a barrier so per-wave vmcnt unions across waves.
// LDS XOR swizzle colbyte ^= (row&7)<<4 on BOTH stage-src and ds_read (rule 21).
// EPI: 0 = tanh->bf16, 1 = sigmoid->bf16
template<int EPI>
__global__ __launch_bounds__(512)
void gemm256(const unsigned short* __restrict__ A,
             const unsigned short* __restrict__ Bt,
             const float* __restrict__ bias,
             unsigned short* __restrict__ outp,
             int N, int K)
{
    __shared__ unsigned short lds[4 * 256 * 64];    // A[2][256][64] | B[2][256][64]
    unsigned short* Al = lds;
    unsigned short* Bl = lds + 2 * 256 * 64;

    const int t = threadIdx.x;
    const int w = t >> 6, l = t & 63;
    const int wr = w >> 2, wc = w & 3;      // wave grid 2 x 4
    const int lr = l & 15, lg = l >> 4;

    // bijective XCD swizzle (nwg = 256)
    const int nwg = gridDim.x * gridDim.y;
    const int bid = blockIdx.y * gridDim.x + blockIdx.x;
    const int q8 = nwg >> 3, r8 = nwg & 7;
    const int xcd = bid & 7, off = bid >> 3;
    const int wgid = (xcd < r8 ? xcd * (q8 + 1) : r8 * (q8 + 1) + (xcd - r8) * q8) + off;
    const int by = wgid / gridDim.x;
    const int bx = wgid % gridDim.x;

    const int row0 = by * 256, col0 = bx * 256;
    const unsigned short* Ab = A  + (size_t)row0 * K;
    const unsigned short* Bb = Bt + (size_t)col0 * K;
    const int NT = K >> 6;

    f32x4 acc[8][4] = {};

    // stage one half (128 rows x 64 cols) of A (mat=0) or B (mat=1), 2 loads/thread
    auto stage_half = [&](int kt, int buf, int mat, int h) {
        const int kb = kt * 128;
        const unsigned short* gb = mat ? Bb : Ab;
        unsigned short* lb = (mat ? Bl : Al) + buf * 16384 + h * 8192;
        #pragma unroll
        for (int qq = 0; qq < 2; qq++) {
            const int id  = qq * 512 + t;
            const int row = h * 128 + (id >> 3);
            const int cb  = (id & 7) * 16;
            const int scb = cb ^ ((row & 7) << 4);
            const char* src = (const char*)gb + (size_t)row * ((size_t)K * 2) + kb + scb;
            __builtin_amdgcn_global_load_lds(
                (const __attribute__((address_space(1))) unsigned int*)src,
                (__attribute__((address_space(3))) unsigned int*)(lb + id * 8), 16, 0, 0);
        }
    };

    // prologue: tile 0 (A-h0, B-h0, B-h1, A-h1); enter loop with A-h1(0) in flight
    stage_half(0, 0, 0, 0);
    stage_half(0, 0, 1, 0);
    stage_half(0, 0, 1, 1);
    stage_half(0, 0, 0, 1);
    asm volatile("s_waitcnt vmcnt(2)" ::: "memory");
    __builtin_amdgcn_s_barrier();

    const int sw = (lr & 7) << 4;
    const int c0 = (lg * 16) ^ sw;          // kk=0 swizzled col byte
    const int c1 = (64 + lg * 16) ^ sw;     // kk=1

    for (int kt = 0; kt < NT; ++kt) {
        const int buf = kt & 1, nb = buf ^ 1;
        const bool pre = (kt + 1 < NT);
        const char* AlB = (const char*)Al + buf * 32768 + (wr * 16 + lr) * 128;
        const char* BlB = (const char*)Bl + buf * 32768 + (wc * 64 + lr) * 128;

        // -------- phase 0: read B (8) + A m0,m1 (4); issue A-h0(t+1); MFMA m0,m1
        bf16x8 bfr[4][2];
        #pragma unroll
        for (int ni = 0; ni < 4; ni++) {
            bfr[ni][0] = *(const bf16x8*)(BlB + ni * 2048 + c0);
            bfr[ni][1] = *(const bf16x8*)(BlB + ni * 2048 + c1);
        }
        #pragma unroll
        for (int p = 0; p < 4; p++) {
            bf16x8 af[2][2];
            #pragma unroll
            for (int ms = 0; ms < 2; ms++) {
                af[ms][0] = *(const bf16x8*)(AlB + (size_t)(2 * p + ms) * 4096 + c0);
                af[ms][1] = *(const bf16x8*)(AlB + (size_t)(2 * p + ms) * 4096 + c1);
            }
            if (pre) {
                if (p == 0)      stage_half(kt + 1, nb, 0, 0);   // A-h0
                else if (p == 1) stage_half(kt + 1, nb, 1, 0);   // B-h0
                else if (p == 2) stage_half(kt + 1, nb, 1, 1);   // B-h1
                else             stage_half(kt + 1, nb, 0, 1);   // A-h1
            }
            __builtin_amdgcn_s_setprio(1);
            #pragma unroll
            for (int ms = 0; ms < 2; ms++)
                #pragma unroll
                for (int ni = 0; ni < 4; ni++) {
                    acc[2 * p + ms][ni] = __builtin_amdgcn_mfma_f32_16x16x32_bf16(
                        af[ms][0], bfr[ni][0], acc[2 * p + ms][ni], 0, 0, 0);
                    acc[2 * p + ms][ni] = __builtin_amdgcn_mfma_f32_16x16x32_bf16(
                        af[ms][1], bfr[ni][1], acc[2 * p + ms][ni], 0, 0, 0);
                }
            __builtin_amdgcn_s_setprio(0);
            if (p == 1) {                       // before phase 2 reads A-half1(t)
                if (pre) asm volatile("s_waitcnt vmcnt(4)" ::: "memory");
                else     asm volatile("s_waitcnt vmcnt(0)" ::: "memory");
            } else if (p == 3) {                // tile boundary
                if (pre) asm volatile("s_waitcnt vmcnt(2)" ::: "memory");
                else     asm volatile("s_waitcnt vmcnt(0)" ::: "memory");
            }
            __builtin_amdgcn_s_barrier();
        }
    }

    // epilogue: m-frag mi at row wr*16 + mi*32; within frag row = lg*4+r, col = lr
    const int colb = col0 + wc * 64;
    #pragma unroll
    for (int ni = 0; ni < 4; ni++) {
        const int cg = colb + ni * 16 + lr;
        const float bv = bias[cg];
        #pragma unroll
        for (int mi = 0; mi < 8; mi++) {
            #pragma unroll
            for (int r = 0; r < 4; r++) {
                const int rg = row0 + wr * 16 + mi * 32 + lg * 4 + r;
                float v = acc[mi][ni][r] + bv;
                if constexpr (EPI == 0) v = tanhf(v);
                else                    v = 1.0f / (1.0f + expf(-v));
                outp[(size_t)rg * N + cg] = f2bf(v);
            }
        }
    }
}

// ---------------------------------------------------------------- 128^2 GEMM (B^T), f32 out
__global__ __launch_bounds__(256)
void gemm_bt_f32(const unsigned short* __restrict__ A,
                 const unsigned short* __restrict__ Bt,
                 const float* __restrict__ bias,
                 float* __restrict__ outp,
                 int N, int K)
{
    __shared__ unsigned short Asl[128 * 32];
    __shared__ unsigned short Bsl[128 * 32];

    const int t  = threadIdx.x;
    const int w  = t >> 6, l = t & 63;
    const int wr = w >> 1, wc = w & 1;
    const int row0 = blockIdx.y * 128;
    const int col0 = blockIdx.x * 128;

    const unsigned short* Ab = A  + (size_t)row0 * K;
    const unsigned short* Bb = Bt + (size_t)col0 * K;

    const int lr = l & 15;
    const int lk = (l >> 4) * 8;

    f32x4 acc[4][4] = {};

    for (int k0 = 0; k0 < K; k0 += 32) {
        __syncthreads();
        #pragma unroll
        for (int q = 0; q < 2; q++) {
            int idx = q * 256 + t;
            int r   = idx >> 2;
            int c8  = (idx & 3) * 8;
            __builtin_amdgcn_global_load_lds(
                (const __attribute__((address_space(1))) unsigned int*)(Ab + (size_t)r * K + k0 + c8),
                (__attribute__((address_space(3))) unsigned int*)(&Asl[idx * 8]), 16, 0, 0);
            __builtin_amdgcn_global_load_lds(
                (const __attribute__((address_space(1))) unsigned int*)(Bb + (size_t)r * K + k0 + c8),
                (__attribute__((address_space(3))) unsigned int*)(&Bsl[idx * 8]), 16, 0, 0);
        }
        __syncthreads();

        bf16x8 af[4], bfr[4];
        #pragma unroll
        for (int mi = 0; mi < 4; mi++)
            af[mi] = *(const bf16x8*)(&Asl[(wr * 64 + mi * 16 + lr) * 32 + lk]);
        #pragma unroll
        for (int ni = 0; ni < 4; ni++)
            bfr[ni] = *(const bf16x8*)(&Bsl[(wc * 64 + ni * 16 + lr) * 32 + lk]);

        #pragma unroll
        for (int mi = 0; mi < 4; mi++)
            #pragma unroll
            for (int ni = 0; ni < 4; ni++)
                acc[mi][ni] = __builtin_amdgcn_mfma_f32_16x16x32_bf16(
                    af[mi], bfr[ni], acc[mi][ni], 0, 0, 0);
    }

    const int colb = col0 + wc * 64;
    const int rowb = row0 + wr * 64 + (l >> 4) * 4;
    #pragma unroll
    for (int ni = 0; ni < 4; ni++) {
        const int cg = colb + ni * 16 + lr;
        const float bv = bias[cg];
        #pragma unroll
        for (int mi = 0; mi < 4; mi++)
            #pragma unroll
            for (int r = 0; r < 4; r++)
                outp[(size_t)(rowb + mi * 16 + r) * N + cg] = acc[mi][ni][r] + bv;
    }
}

// ---------------------------------------------------------------- v = proj @ curv_feat
__global__ __launch_bounds__(256)
void proj_cf(const float* __restrict__ proj, const float* __restrict__ cf,
             float* __restrict__ v)
{
    int i = blockIdx.x * 256 + threadIdx.x;
    if (i < IND) {
        float s = 0.f;
        #pragma unroll
        for (int j = 0; j < 16; j++) s += proj[i * 16 + j] * cf[j];
        v[i] = s;
    }
}

// ---------------------------------------------------------------- Poincare layer
__global__ __launch_bounds__(256)
void poincare_kernel(const unsigned short* __restrict__ hb,
                     const unsigned short* __restrict__ ub,
                     const float* __restrict__ c,
                     unsigned short* __restrict__ zb)
{
    const int row = blockIdx.x;
    const int t = threadIdx.x;
    const size_t base = (size_t)row * HIDD;

    float hv[16], uv[16];
    float h2 = 0.f, u2 = 0.f, hu = 0.f;
    #pragma unroll
    for (int q = 0; q < 2; q++) {
        const int e0 = (q * 256 + t) * 8;
        uint4 hc = *(const uint4*)(hb + base + e0);
        uint4 uc = *(const uint4*)(ub + base + e0);
        const unsigned int hw[4] = {hc.x, hc.y, hc.z, hc.w};
        const unsigned int uw[4] = {uc.x, uc.y, uc.z, uc.w};
        #pragma unroll
        for (int i = 0; i < 4; i++) {
            float h0 = bf2f(hw[i] & 0xFFFFu), h1 = bf2f(hw[i] >> 16);
            float u0 = bf2f(uw[i] & 0xFFFFu), u1 = bf2f(uw[i] >> 16);
            hv[q * 8 + 2 * i]     = h0; hv[q * 8 + 2 * i + 1] = h1;
            uv[q * 8 + 2 * i]     = u0; uv[q * 8 + 2 * i + 1] = u1;
            h2 += h0 * h0 + h1 * h1;
            u2 += u0 * u0 + u1 * u1;
            hu += h0 * u0 + h1 * u1;
        }
    }
    #pragma unroll
    for (int o = 32; o > 0; o >>= 1) {
        h2 += __shfl_down(h2, o, 64);
        u2 += __shfl_down(u2, o, 64);
        hu += __shfl_down(hu, o, 64);
    }
    __shared__ float red[3][4];
    const int w = t >> 6;
    if ((t & 63) == 0) { red[0][w] = h2; red[1][w] = u2; red[2][w] = hu; }
    __syncthreads();
    h2 = red[0][0] + red[0][1] + red[0][2] + red[0][3];
    u2 = red[1][0] + red[1][1] + red[1][2] + red[1][3];
    hu = red[2][0] + red[2][1] + red[2][2] + red[2][3];

    const float cc = c[row];
    const float sc = sqrtf(cc);
    float nh = fmaxf(sqrtf(h2), EPSV);
    float nu = fmaxf(sqrtf(u2), EPSV);
    float ah = fminf(fmaxf(sc * nh, EPSV), 1.0f - 1e-5f);
    float au = fminf(fmaxf(sc * nu, EPSV), 1.0f - 1e-5f);
    float ath = 0.5f * log1pf(2.0f * ah / (1.0f - ah));
    float atu = 0.5f * log1pf(2.0f * au / (1.0f - au));
    float alpha = tanhf((1.0f - T_C) * ath) / (sc * nh);
    float beta  = tanhf(T_C * atu) / (sc * nu);
    float x2 = alpha * alpha * h2;
    float y2 = beta * beta * u2;
    float xy = alpha * beta * hu;
    float den = 1.0f + 2.0f * cc * xy + cc * cc * x2 * y2;
    den = fmaxf(den, EPSV);
    float ca = (1.0f + 2.0f * cc * xy + cc * y2) * alpha / den;
    float cb = (1.0f - cc * x2) * beta / den;
    if (isnan(ca) || isnan(cb)) { ca = 1.0f; cb = 0.0f; }

    #pragma unroll
    for (int q = 0; q < 2; q++) {
        const int e0 = (q * 256 + t) * 8;
        unsigned int ow[4];
        #pragma unroll
        for (int i = 0; i < 4; i++) {
            float z0 = ca * hv[q * 8 + 2 * i]     + cb * uv[q * 8 + 2 * i];
            float z1 = ca * hv[q * 8 + 2 * i + 1] + cb * uv[q * 8 + 2 * i + 1];
            ow[i] = (unsigned int)f2bf(z0) | ((unsigned int)f2bf(z1) << 16);
        }
        *(uint4*)(zb + base + e0) = make_uint4(ow[0], ow[1], ow[2], ow[3]);
    }
}

// ---------------------------------------------------------------------------
extern "C" void kernel_launch(void* const* d_in, const int* in_sizes, int n_in,
                              void* d_out, int out_size, void* d_ws, size_t ws_size,
                              hipStream_t stream)
{
    const float* x    = (const float*)d_in[0];
    const float* W1   = (const float*)d_in[1];
    const float* b1   = (const float*)d_in[2];
    const float* W2   = (const float*)d_in[3];
    const float* b2   = (const float*)d_in[4];
    const float* Wout = (const float*)d_in[5];
    const float* bout = (const float*)d_in[6];
    const float* cf   = (const float*)d_in[7];
    const float* cs   = (const float*)d_in[8];
    const float* proj = (const float*)d_in[9];
    float* out = (float*)d_out;

    char* ws = (char*)d_ws;
    unsigned short* x_bf = (unsigned short*)(ws);               // 32 MiB (reused as z_bf)
    unsigned short* w_bf = (unsigned short*)(ws + (33554432));  // 32 MiB (W1T/W2T/WoutT)
    unsigned short* h_bf = (unsigned short*)(ws + (67108864));  // 32 MiB
    unsigned short* u_bf = (unsigned short*)(ws + (100663296)); // 32 MiB
    float* vvec = (float*)(ws + 134217728);                     // 16 KiB
    float* cvec = (float*)(ws + 134217728 + 16384);             // 16 KiB

    // 1. curvature prep + fused cast/row-dot
    proj_cf<<<IND / 256, 256, 0, stream>>>(proj, cf, vvec);
    cast_curv<<<BATCH, 256, 0, stream>>>(x, vvec, cs, x_bf, cvec);

    // 2. h = tanh(x @ W1 + b1)
    transpose_cast<<<dim3(HIDD / 32, IND / 32), 256, 0, stream>>>(W1, w_bf, IND, HIDD);
    gemm256<0><<<dim3(HIDD / 256, BATCH / 256), 512, 0, stream>>>(x_bf, w_bf, b1, h_bf, HIDD, IND);

    // 3. u = sigmoid(h @ W2 + b2)
    transpose_cast<<<dim3(HIDD / 32, HIDD / 32), 256, 0, stream>>>(W2, w_bf, HIDD, HIDD);
    gemm256<1><<<dim3(HIDD / 256, BATCH / 256), 512, 0, stream>>>(h_bf, w_bf, b2, u_bf, HIDD, HIDD);

    // 4. z = poincare(h, u, c)   (z overwrites x_bf)
    poincare_kernel<<<BATCH, 256, 0, stream>>>(h_bf, u_bf, cvec, x_bf);

    // 5. out = z @ Wout + bout
    transpose_cast<<<dim3(OUTD / 32, HIDD / 32), 256, 0, stream>>>(Wout, w_bf, HIDD, OUTD);
    gemm_bt_f32<<<dim3(OUTD / 128, BATCH / 128), 256, 0, stream>>>(x_bf, w_bf, bout, out, OUTD, HIDD);
}